// Round 1
// baseline (847.909 us; speedup 1.0000x reference)
//
#include <hip/hip_runtime.h>
#include <math.h>

// Workspace layout (floats):
//   [0, 40960)        td accumulator (4096 x 10)
//   [40960, 81920)    sc accumulator (4096 x 10)
//   [81920, 90668)    combined conv kernel K[c][d][dx][f] (3*27*27*4)
#define TD_OFF 0
#define SC_OFF 40960
#define K_OFF  81920

__device__ __forceinline__ float eluf(float v) { return v > 0.f ? v : expm1f(v); }

// K[c][d][dx][f] = sum_m dw[d][dx][c][m] * pw[c*5+m][f]
__global__ __launch_bounds__(256) void make_K(const float* __restrict__ dw,
                                              const float* __restrict__ pw,
                                              float* __restrict__ K) {
    int i = blockIdx.x * 256 + threadIdx.x;
    if (i >= 3 * 27 * 27 * 4) return;
    int f = i & 3;
    int r = i >> 2;
    int dx = r % 27; r /= 27;
    int d  = r % 27;
    int c  = r / 27;
    float s = 0.f;
#pragma unroll
    for (int m = 0; m < 5; m++)
        s = fmaf(dw[((d * 27 + dx) * 3 + c) * 5 + m], pw[(c * 5 + m) * 4 + f], s);
    K[i] = s;
}

// One thread per (sample, row) sequence: 32 LSTM steps, fused partial dot with
// W_td rows [row*128, row*128+128). Reduce the 32 rows of a sample across a
// 32-lane half-wave, direct store (each sample owned by exactly one half-wave).
__global__ __launch_bounds__(256) void lstm_td(const float* __restrict__ x,
                                               const float* __restrict__ W,
                                               const float* __restrict__ U,
                                               const float* __restrict__ Wtd,
                                               float* __restrict__ td_out) {
    __shared__ float sW[48];
    __shared__ float sU[64];
    int t = threadIdx.x;
    if (t < 48) sW[t] = W[t];
    else if (t >= 128 && t < 192) sU[t - 128] = U[t - 128];
    __syncthreads();

    int n = blockIdx.x * 256 + t;   // n in [0, 131072): n = b*32 + row
    int row = n & 31;
    const float* xp = x + (size_t)n * 96;
    const float* wtd_base = Wtd + (size_t)row * 128 * 10;

    float h0 = 0, h1 = 0, h2 = 0, h3 = 0;
    float c0 = 0, c1 = 0, c2 = 0, c3 = 0;
    float acc[10];
#pragma unroll
    for (int j = 0; j < 10; j++) acc[j] = 0.f;

    for (int tt = 0; tt < 32; tt++) {
        float x0 = xp[tt * 3 + 0], x1 = xp[tt * 3 + 1], x2 = xp[tt * 3 + 2];
        float z[16];
#pragma unroll
        for (int k = 0; k < 16; k++)
            z[k] = x0 * sW[k] + x1 * sW[16 + k] + x2 * sW[32 + k]
                 + h0 * sU[k] + h1 * sU[16 + k] + h2 * sU[32 + k] + h3 * sU[48 + k];

        float ig0 = eluf(z[0]),  ig1 = eluf(z[1]),  ig2 = eluf(z[2]),  ig3 = eluf(z[3]);
        float fg0 = eluf(z[4]),  fg1 = eluf(z[5]),  fg2 = eluf(z[6]),  fg3 = eluf(z[7]);
        float og0 = eluf(z[12]), og1 = eluf(z[13]), og2 = eluf(z[14]), og3 = eluf(z[15]);

        // softmax over z[8..11]
        float zm = fmaxf(fmaxf(z[8], z[9]), fmaxf(z[10], z[11]));
        float e0 = expf(z[8] - zm), e1 = expf(z[9] - zm);
        float e2 = expf(z[10] - zm), e3 = expf(z[11] - zm);
        float inv = 1.f / (e0 + e1 + e2 + e3);
        c0 = fg0 * c0 + ig0 * (e0 * inv);
        c1 = fg1 * c1 + ig1 * (e1 * inv);
        c2 = fg2 * c2 + ig2 * (e2 * inv);
        c3 = fg3 * c3 + ig3 * (e3 * inv);

        // softmax over c
        float cm = fmaxf(fmaxf(c0, c1), fmaxf(c2, c3));
        float q0 = expf(c0 - cm), q1 = expf(c1 - cm);
        float q2 = expf(c2 - cm), q3 = expf(c3 - cm);
        float qinv = 1.f / (q0 + q1 + q2 + q3);
        h0 = og0 * (q0 * qinv); h1 = og1 * (q1 * qinv);
        h2 = og2 * (q2 * qinv); h3 = og3 * (q3 * qinv);

        // td partial: flatten index i = row*128 + tt*4 + k
        const float* wr = wtd_base + tt * 40;
#pragma unroll
        for (int j = 0; j < 10; j++)
            acc[j] += h0 * wr[j] + h1 * wr[10 + j] + h2 * wr[20 + j] + h3 * wr[30 + j];
    }

    // reduce over 32 rows (half-wave); offsets <32 keep 32-lane halves separate
#pragma unroll
    for (int off = 16; off >= 1; off >>= 1) {
#pragma unroll
        for (int j = 0; j < 10; j++) acc[j] += __shfl_xor(acc[j], off, 64);
    }
    int lane = t & 63;
    if (lane == 0 || lane == 32) {
        int b = n >> 5;
#pragma unroll
        for (int j = 0; j < 10; j++) td_out[b * 10 + j] = acc[j];
    }
}

// One block per image. Zero-padded channel-planar image in LDS (3 x 58 x 58).
// Thread = (w, 4-row strip). Inner loop: per (c,dx), slide over 30 input rows
// with rolling 4 uniform K-quads; 1 ds_read per 16 fp32 FMAs -> VALU-bound.
__global__ __launch_bounds__(256) void conv_sc(const float* __restrict__ x,
                                               const float* __restrict__ K,
                                               const float* __restrict__ Wsc,
                                               const float* __restrict__ bias,
                                               float* __restrict__ sc_out) {
    __shared__ float xp[3 * 58 * 58];
    __shared__ float red[4][10];
    int t = threadIdx.x;
    int b = blockIdx.x;

    for (int i = t; i < 3 * 58 * 58; i += 256) xp[i] = 0.f;
    __syncthreads();
    const float* xb = x + (size_t)b * 3072;  // x[b][h][w][c]
    for (int i = t; i < 3072; i += 256) {
        int c = i % 3;
        int wcol = (i / 3) & 31;
        int hrow = i / 96;
        xp[(c * 58 + hrow + 13) * 58 + (wcol + 13)] = xb[i];
    }
    __syncthreads();

    int w = t & 31, g = t >> 5;
    int hb = g * 4;                // this thread owns output rows hb..hb+3, col w
    float acc[4][4];
#pragma unroll
    for (int q = 0; q < 4; q++)
#pragma unroll
        for (int f = 0; f < 4; f++) acc[q][f] = 0.f;

    for (int c = 0; c < 3; c++) {
        for (int dx = 0; dx < 27; dx++) {
            const float* xcol = &xp[(c * 58 + hb) * 58 + (w + dx)];
            const float* kb = K + ((c * 27) * 27 + dx) * 4;  // + d*108 for K[c][d][dx][.]
            float4 kq[4];
#pragma unroll
            for (int s = 0; s < 30; s++) {
                if (s <= 26) kq[s & 3] = *(const float4*)(kb + s * 108);
                float xv = xcol[s * 58];
#pragma unroll
                for (int q = 0; q < 4; q++) {
                    int d = s - q;
                    if (d >= 0 && d <= 26) {
                        float4 kk = kq[d & 3];
                        acc[q][0] = fmaf(xv, kk.x, acc[q][0]);
                        acc[q][1] = fmaf(xv, kk.y, acc[q][1]);
                        acc[q][2] = fmaf(xv, kk.z, acc[q][2]);
                        acc[q][3] = fmaf(xv, kk.w, acc[q][3]);
                    }
                }
            }
        }
    }

    // sigmoid + partial dot with W_sc, flatten index i = ((hb+q)*32+w)*4+f
    float part[10];
#pragma unroll
    for (int j = 0; j < 10; j++) part[j] = 0.f;
#pragma unroll
    for (int q = 0; q < 4; q++) {
#pragma unroll
        for (int f = 0; f < 4; f++) {
            float sg = 1.f / (1.f + expf(-(acc[q][f] + bias[f])));
            const float* wr = Wsc + (size_t)(((hb + q) * 32 + w) * 4 + f) * 10;
#pragma unroll
            for (int j = 0; j < 10; j++) part[j] = fmaf(sg, wr[j], part[j]);
        }
    }

#pragma unroll
    for (int off = 32; off >= 1; off >>= 1) {
#pragma unroll
        for (int j = 0; j < 10; j++) part[j] += __shfl_xor(part[j], off, 64);
    }
    int wave = t >> 6;
    if ((t & 63) == 0) {
#pragma unroll
        for (int j = 0; j < 10; j++) red[wave][j] = part[j];
    }
    __syncthreads();
    if (t < 10) sc_out[b * 10 + t] = red[0][t] + red[1][t] + red[2][t] + red[3][t];
}

__global__ __launch_bounds__(256) void finalize(const float* __restrict__ td,
                                                const float* __restrict__ sc,
                                                float* __restrict__ out, int n) {
    int i = blockIdx.x * 256 + threadIdx.x;
    if (i < n) {
        float a = td[i], s = sc[i];
        float tol = 1e-6f + 1e-6f * fabsf(s);
        out[i] = (fabsf(a - s) <= tol) ? 1.0f : 0.0f;
    }
}

extern "C" void kernel_launch(void* const* d_in, const int* in_sizes, int n_in,
                              void* d_out, int out_size, void* d_ws, size_t ws_size,
                              hipStream_t stream) {
    const float* x    = (const float*)d_in[0];
    const float* W    = (const float*)d_in[1];
    const float* U    = (const float*)d_in[2];
    const float* dw   = (const float*)d_in[3];
    const float* pw   = (const float*)d_in[4];
    const float* bias = (const float*)d_in[5];
    const float* Wtd  = (const float*)d_in[6];
    const float* Wsc  = (const float*)d_in[7];

    float* ws     = (float*)d_ws;
    float* td_acc = ws + TD_OFF;
    float* sc_acc = ws + SC_OFF;
    float* K      = ws + K_OFF;

    make_K<<<(3 * 27 * 27 * 4 + 255) / 256, 256, 0, stream>>>(dw, pw, K);
    lstm_td<<<512, 256, 0, stream>>>(x, W, U, Wtd, td_acc);
    conv_sc<<<4096, 256, 0, stream>>>(x, K, Wsc, bias, sc_acc);
    finalize<<<(out_size + 255) / 256, 256, 0, stream>>>(td_acc, sc_acc, (float*)d_out, out_size);
}

// Round 2
// 676.090 us; speedup vs baseline: 1.2541x; 1.2541x over previous
//
#include <hip/hip_runtime.h>
#include <math.h>

// ---------------- Workspace layout ----------------
// floats:   [0, 40960)        td accumulator (4096 x 10)
//           [40960, 81920)    sc accumulator (4096 x 10)
//           [81920, 90668)    combined conv kernel K[c][d][dx][f] (3*27*27*4)
// bytes:    [362672, 362672+1658880)  Bg: bf16 hi/lo split weight slabs
//           Bg[s][plane][n][20 ushort] for s in 0..161 (slab = 10240 B)
#define TD_OFF 0
#define SC_OFF 40960
#define K_OFF  81920
#define BG_BYTE_OFF 362672

typedef __bf16 bf16x8 __attribute__((ext_vector_type(8)));
typedef float f32x16 __attribute__((ext_vector_type(16)));

union FragU { bf16x8 v; uint2 u2[2]; };

__device__ __forceinline__ f32x16 mfma16(bf16x8 a, bf16x8 b, f32x16 c) {
    return __builtin_amdgcn_mfma_f32_32x32x16_bf16(a, b, c, 0, 0, 0);
}

__device__ __forceinline__ float eluf(float v) { return v > 0.f ? v : expm1f(v); }

// ---------------- prep: combined conv kernel ----------------
// K[c][d][dx][f] = sum_m dw[d][dx][c][m] * pw[c*5+m][f]
__global__ __launch_bounds__(256) void make_K(const float* __restrict__ dw,
                                              const float* __restrict__ pw,
                                              float* __restrict__ K) {
    int i = blockIdx.x * 256 + threadIdx.x;
    if (i >= 3 * 27 * 27 * 4) return;
    int f = i & 3;
    int r = i >> 2;
    int dx = r % 27; r /= 27;
    int d  = r % 27;
    int c  = r / 27;
    float s = 0.f;
#pragma unroll
    for (int m = 0; m < 5; m++)
        s = fmaf(dw[((d * 27 + dx) * 3 + c) * 5 + m], pw[(c * 5 + m) * 4 + f], s);
    K[i] = s;
}

// ---------------- prep: B matrix (bf16 hi/lo split, LDS-staging layout) ----
// GEMM: C[m=(b,h)][n=(w,f)] = sum_k A[m][k] B[k][n],  k = (c*27+d)*32 + xi
// B[k][n] = K[c][d][xi-w+13][f] when 0<=xi-w+13<27 else 0.
// Chunk s = ((c*27+d)*2 + half), covers k-range xi = half*16 .. +16.
// Layout: Bg[s][plane(hi=0,lo=1)][n 0..127][20 ushort (16 k + 4 pad)]
__global__ __launch_bounds__(256) void make_B(const float* __restrict__ K,
                                              unsigned short* __restrict__ Bg) {
    int gid = blockIdx.x * 256 + threadIdx.x;
    if (gid >= 162 * 128) return;
    int n = gid & 127;
    int s = gid >> 7;
    int half = s & 1;
    int cd = s >> 1;
    int c = cd / 27, d = cd % 27;
    int w = n >> 2, f = n & 3;
    unsigned short* dsth = Bg + (size_t)s * 5120 + n * 20;
    unsigned short* dstl = dsth + 2560;
#pragma unroll
    for (int k = 0; k < 16; k++) {
        int xi = half * 16 + k;
        int dx = xi - w + 13;
        float v = (dx >= 0 && dx < 27) ? K[((c * 27 + d) * 27 + dx) * 4 + f] : 0.f;
        __bf16 h = (__bf16)v;
        __bf16 l = (__bf16)(v - (float)h);
        dsth[k] = __builtin_bit_cast(unsigned short, h);
        dstl[k] = __builtin_bit_cast(unsigned short, l);
    }
#pragma unroll
    for (int k = 16; k < 20; k++) { dsth[k] = 0; dstl[k] = 0; }
}

// ---------------- LSTM branch (unchanged math, float4 x loads) -------------
__global__ __launch_bounds__(256) void lstm_td(const float* __restrict__ x,
                                               const float* __restrict__ W,
                                               const float* __restrict__ U,
                                               const float* __restrict__ Wtd,
                                               float* __restrict__ td_out) {
    __shared__ float sW[48];
    __shared__ float sU[64];
    int t = threadIdx.x;
    if (t < 48) sW[t] = W[t];
    else if (t >= 128 && t < 192) sU[t - 128] = U[t - 128];
    __syncthreads();

    int n = blockIdx.x * 256 + t;   // n = b*32 + row
    int row = n & 31;
    const float4* xp4 = (const float4*)(x + (size_t)n * 96);
    const float* wtd_base = Wtd + (size_t)row * 128 * 10;

    float h0 = 0, h1 = 0, h2 = 0, h3 = 0;
    float c0 = 0, c1 = 0, c2 = 0, c3 = 0;
    float acc[10];
#pragma unroll
    for (int j = 0; j < 10; j++) acc[j] = 0.f;

    for (int g = 0; g < 8; g++) {
        float4 q0 = xp4[g * 3 + 0], q1 = xp4[g * 3 + 1], q2 = xp4[g * 3 + 2];
        float xr[12] = {q0.x, q0.y, q0.z, q0.w, q1.x, q1.y,
                        q1.z, q1.w, q2.x, q2.y, q2.z, q2.w};
#pragma unroll
        for (int st = 0; st < 4; st++) {
            int tt = g * 4 + st;
            float x0 = xr[st * 3 + 0], x1 = xr[st * 3 + 1], x2 = xr[st * 3 + 2];
            float z[16];
#pragma unroll
            for (int k = 0; k < 16; k++)
                z[k] = x0 * sW[k] + x1 * sW[16 + k] + x2 * sW[32 + k]
                     + h0 * sU[k] + h1 * sU[16 + k] + h2 * sU[32 + k] + h3 * sU[48 + k];

            float ig0 = eluf(z[0]),  ig1 = eluf(z[1]),  ig2 = eluf(z[2]),  ig3 = eluf(z[3]);
            float fg0 = eluf(z[4]),  fg1 = eluf(z[5]),  fg2 = eluf(z[6]),  fg3 = eluf(z[7]);
            float og0 = eluf(z[12]), og1 = eluf(z[13]), og2 = eluf(z[14]), og3 = eluf(z[15]);

            float zm = fmaxf(fmaxf(z[8], z[9]), fmaxf(z[10], z[11]));
            float e0 = expf(z[8] - zm), e1 = expf(z[9] - zm);
            float e2 = expf(z[10] - zm), e3 = expf(z[11] - zm);
            float inv = 1.f / (e0 + e1 + e2 + e3);
            c0 = fg0 * c0 + ig0 * (e0 * inv);
            c1 = fg1 * c1 + ig1 * (e1 * inv);
            c2 = fg2 * c2 + ig2 * (e2 * inv);
            c3 = fg3 * c3 + ig3 * (e3 * inv);

            float cm = fmaxf(fmaxf(c0, c1), fmaxf(c2, c3));
            float q0e = expf(c0 - cm), q1e = expf(c1 - cm);
            float q2e = expf(c2 - cm), q3e = expf(c3 - cm);
            float qinv = 1.f / (q0e + q1e + q2e + q3e);
            h0 = og0 * (q0e * qinv); h1 = og1 * (q1e * qinv);
            h2 = og2 * (q2e * qinv); h3 = og3 * (q3e * qinv);

            const float* wr = wtd_base + tt * 40;
#pragma unroll
            for (int j = 0; j < 10; j++)
                acc[j] += h0 * wr[j] + h1 * wr[10 + j] + h2 * wr[20 + j] + h3 * wr[30 + j];
        }
    }

#pragma unroll
    for (int off = 16; off >= 1; off >>= 1) {
#pragma unroll
        for (int j = 0; j < 10; j++) acc[j] += __shfl_xor(acc[j], off, 64);
    }
    int lane = t & 63;
    if (lane == 0 || lane == 32) {
        int b = n >> 5;
#pragma unroll
        for (int j = 0; j < 10; j++) td_out[b * 10 + j] = acc[j];
    }
}

// ---------------- conv branch: MFMA implicit GEMM --------------------------
// Block = 4 images (M-tile 32 = one image), N = 128 = (w,f).
// Wave wv: images {(wv>>1)*2, +1} x N-tiles {(wv&1)*2, +1}.
// A staged once in LDS as bf16 hi/lo planes: [img][c][row] record of 136 B
//   (32 hi bf16 @0, 32 lo bf16 @64, 8 pad) -> 2-way-free banks, b64-aligned.
// B staged per 16-k chunk from precomputed Bg (software-pipelined).
#define A_OFF 0
#define A_BYTES 52224        /* 4*3*32*136 */
#define SB_OFF 52224
#define SB_BYTES 10240
#define ZOFF 62464           /* 128 B zero row */
#define SRED_OFF 62592       /* 4 waves * 2 img * 10 floats */
#define LDS_BYTES 62912

__global__ __launch_bounds__(256, 2) void conv_sc(const float* __restrict__ x,
                                                  const unsigned short* __restrict__ Bg,
                                                  const float* __restrict__ Wsc,
                                                  const float* __restrict__ bias,
                                                  float* __restrict__ sc_out) {
    __shared__ char LDS[LDS_BYTES] __attribute__((aligned(16)));
    int t = threadIdx.x;
    int l = t & 63;
    int wv = t >> 6;
    int m = l & 31;
    int sub = (l >> 5) * 16;

    // ---- stage A: load 4 images, split to bf16 hi/lo planes ----
    const float* xb = x + (size_t)blockIdx.x * 12288;
    for (int img = 0; img < 4; img++) {
        const float4* xi4 = (const float4*)(xb + img * 3072);
#pragma unroll
        for (int i = 0; i < 3; i++) {
            int fi = i * 256 + t;           // 768 float4 per image
            float4 q = xi4[fi];
            float vals[4] = {q.x, q.y, q.z, q.w};
            int p = fi * 4;
#pragma unroll
            for (int e = 0; e < 4; e++) {
                int pe = p + e;
                int c = pe % 3;
                int hw = pe / 3;
                int wc = hw & 31;
                int hr = hw >> 5;
                int rec = A_OFF + ((img * 3 + c) * 32 + hr) * 136 + wc * 2;
                float v = vals[e];
                __bf16 hb = (__bf16)v;
                __bf16 lb = (__bf16)(v - (float)hb);
                *(__bf16*)(LDS + rec) = hb;
                *(__bf16*)(LDS + rec + 64) = lb;
            }
        }
    }
    if (t < 32) *(float*)(LDS + ZOFF + t * 4) = 0.f;

    // ---- prologue: load B slab 0 into regs ----
    const float4* bgf = (const float4*)Bg;
    float4 breg[3];
#pragma unroll
    for (int i = 0; i < 3; i++) {
        int idx = i * 256 + t;
        if (idx < 640) breg[i] = bgf[idx];
    }

    int imgpair = wv >> 1;
    int img0 = imgpair * 2;
    int ntbase = (wv & 1) * 2;

    f32x16 acc00 = {0,0,0,0,0,0,0,0,0,0,0,0,0,0,0,0};
    f32x16 acc01 = acc00, acc10 = acc00, acc11 = acc00;

    int c = 0, d = 0, half = 0;
    for (int s = 0; s < 162; s++) {
        __syncthreads();   // prior chunk's frag reads complete
#pragma unroll
        for (int i = 0; i < 3; i++) {
            int idx = i * 256 + t;
            if (idx < 640) *(float4*)(LDS + SB_OFF + idx * 16) = breg[i];
        }
        __syncthreads();   // slab visible
        if (s < 161) {
            const float4* nb = bgf + (size_t)(s + 1) * 640;
#pragma unroll
            for (int i = 0; i < 3; i++) {
                int idx = i * 256 + t;
                if (idx < 640) breg[i] = nb[idx];
            }
        }

        // A fragments (vertical SAME via zero-row select)
        int rowIdx = m + d - 13;
        bool valid = (unsigned)rowIdx < 32u;
        int aoff = A_OFF + ((img0 * 3 + c) * 32 + rowIdx) * 136 + half * 32 + sub;
        int base0 = valid ? aoff : ZOFF;
        int base1 = valid ? (aoff + 13056) : ZOFF;

        FragU ah0, al0, ah1, al1;
        ah0.u2[0] = *(const uint2*)(LDS + base0);
        ah0.u2[1] = *(const uint2*)(LDS + base0 + 8);
        al0.u2[0] = *(const uint2*)(LDS + base0 + 64);
        al0.u2[1] = *(const uint2*)(LDS + base0 + 72);
        ah1.u2[0] = *(const uint2*)(LDS + base1);
        ah1.u2[1] = *(const uint2*)(LDS + base1 + 8);
        al1.u2[0] = *(const uint2*)(LDS + base1 + 64);
        al1.u2[1] = *(const uint2*)(LDS + base1 + 72);

        // B fragments
        int bb0 = SB_OFF + ((ntbase + 0) * 32 + m) * 40 + sub;
        int bb1 = SB_OFF + ((ntbase + 1) * 32 + m) * 40 + sub;
        FragU bh0, bl0, bh1, bl1;
        bh0.u2[0] = *(const uint2*)(LDS + bb0);
        bh0.u2[1] = *(const uint2*)(LDS + bb0 + 8);
        bl0.u2[0] = *(const uint2*)(LDS + bb0 + 5120);
        bl0.u2[1] = *(const uint2*)(LDS + bb0 + 5128);
        bh1.u2[0] = *(const uint2*)(LDS + bb1);
        bh1.u2[1] = *(const uint2*)(LDS + bb1 + 8);
        bl1.u2[0] = *(const uint2*)(LDS + bb1 + 5120);
        bl1.u2[1] = *(const uint2*)(LDS + bb1 + 5128);

        // 3-product bf16 split: hh + hl + lh
        acc00 = mfma16(ah0.v, bh0.v, acc00);
        acc00 = mfma16(ah0.v, bl0.v, acc00);
        acc00 = mfma16(al0.v, bh0.v, acc00);
        acc01 = mfma16(ah0.v, bh1.v, acc01);
        acc01 = mfma16(ah0.v, bl1.v, acc01);
        acc01 = mfma16(al0.v, bh1.v, acc01);
        acc10 = mfma16(ah1.v, bh0.v, acc10);
        acc10 = mfma16(ah1.v, bl0.v, acc10);
        acc10 = mfma16(al1.v, bh0.v, acc10);
        acc11 = mfma16(ah1.v, bh1.v, acc11);
        acc11 = mfma16(ah1.v, bl1.v, acc11);
        acc11 = mfma16(al1.v, bh1.v, acc11);

        half ^= 1;
        if (!half) { d++; if (d == 27) { d = 0; c++; } }
    }

    // ---- epilogue: bias + sigmoid + W_sc partial dot + reductions ----
    float b4[4];
#pragma unroll
    for (int i = 0; i < 4; i++) b4[i] = bias[i];

    float part[2][10];
#pragma unroll
    for (int i = 0; i < 2; i++)
#pragma unroll
        for (int j = 0; j < 10; j++) part[i][j] = 0.f;

    f32x16 accs[2][2] = {{acc00, acc01}, {acc10, acc11}};
#pragma unroll
    for (int i2 = 0; i2 < 2; i2++) {
#pragma unroll
        for (int j2 = 0; j2 < 2; j2++) {
            int ncol = (ntbase + j2) * 32 + m;
            int wcol = ncol >> 2;
            int f = ncol & 3;
            f32x16 a = accs[i2][j2];
#pragma unroll
            for (int r = 0; r < 16; r++) {
                int h = (r & 3) + 8 * (r >> 2) + 4 * (l >> 5);
                float v = a[r] + b4[f];
                float sg = 1.f / (1.f + expf(-v));
                const float* wr = Wsc + (size_t)((h * 32 + wcol) * 4 + f) * 10;
#pragma unroll
                for (int j = 0; j < 10; j++) part[i2][j] = fmaf(sg, wr[j], part[i2][j]);
            }
        }
    }

#pragma unroll
    for (int off = 32; off >= 1; off >>= 1) {
#pragma unroll
        for (int i2 = 0; i2 < 2; i2++)
#pragma unroll
            for (int j = 0; j < 10; j++) part[i2][j] += __shfl_xor(part[i2][j], off, 64);
    }
    if (l == 0) {
        float* red = (float*)(LDS + SRED_OFF);
#pragma unroll
        for (int i2 = 0; i2 < 2; i2++)
#pragma unroll
            for (int j = 0; j < 10; j++) red[(wv * 2 + i2) * 10 + j] = part[i2][j];
    }
    __syncthreads();
    if (t < 40) {
        int img = t / 10, j = t % 10;
        const float* red = (const float*)(LDS + SRED_OFF);
        int pair = img >> 1, i2 = img & 1;
        float sv = red[((pair * 2) * 2 + i2) * 10 + j] + red[((pair * 2 + 1) * 2 + i2) * 10 + j];
        sc_out[(blockIdx.x * 4 + img) * 10 + j] = sv;
    }
}

__global__ __launch_bounds__(256) void finalize(const float* __restrict__ td,
                                                const float* __restrict__ sc,
                                                float* __restrict__ out, int n) {
    int i = blockIdx.x * 256 + threadIdx.x;
    if (i < n) {
        float a = td[i], s = sc[i];
        float tol = 1e-6f + 1e-6f * fabsf(s);
        out[i] = (fabsf(a - s) <= tol) ? 1.0f : 0.0f;
    }
}

extern "C" void kernel_launch(void* const* d_in, const int* in_sizes, int n_in,
                              void* d_out, int out_size, void* d_ws, size_t ws_size,
                              hipStream_t stream) {
    const float* x    = (const float*)d_in[0];
    const float* W    = (const float*)d_in[1];
    const float* U    = (const float*)d_in[2];
    const float* dw   = (const float*)d_in[3];
    const float* pw   = (const float*)d_in[4];
    const float* bias = (const float*)d_in[5];
    const float* Wtd  = (const float*)d_in[6];
    const float* Wsc  = (const float*)d_in[7];

    float* ws     = (float*)d_ws;
    float* td_acc = ws + TD_OFF;
    float* sc_acc = ws + SC_OFF;
    float* K      = ws + K_OFF;
    unsigned short* Bg = (unsigned short*)((char*)d_ws + BG_BYTE_OFF);

    make_K<<<(3 * 27 * 27 * 4 + 255) / 256, 256, 0, stream>>>(dw, pw, K);
    make_B<<<(162 * 128 + 255) / 256, 256, 0, stream>>>(K, Bg);
    lstm_td<<<512, 256, 0, stream>>>(x, W, U, Wtd, td_acc);
    conv_sc<<<1024, 256, 0, stream>>>(x, Bg, Wsc, bias, sc_acc);
    finalize<<<(out_size + 255) / 256, 256, 0, stream>>>(td_acc, sc_acc, (float*)d_out, out_size);
}

// Round 3
// 426.394 us; speedup vs baseline: 1.9886x; 1.5856x over previous
//
#include <hip/hip_runtime.h>
#include <math.h>

// ---------------- Workspace layout ----------------
// floats:   [0, 40960)          td accumulator (4096 x 10)
//           [40960, 81920)      sc accumulator (4096 x 10)
//           [81920, 90668)      combined conv kernel K[c][d][dx][f]
//           [90672, 131632)     Wtdr[tt][row][k][j] reordered W_td
// bytes:    [526528, 526528+1327104)  Bg2: bf16 hi/lo B in MFMA-fragment order
//           Bg2[s][plane][n][16k] : chunk slab = 8192 B, plane = 4096 B
#define TD_OFF 0
#define SC_OFF 40960
#define K_OFF  81920
#define WTDR_OFF 90672
#define BG_BYTE_OFF 526528

typedef __bf16 bf16x8 __attribute__((ext_vector_type(8)));
typedef float f32x16 __attribute__((ext_vector_type(16)));

union FragU { bf16x8 v; uint2 u2[2]; };
union BF4  { float4 f; bf16x8 v; };

__device__ __forceinline__ f32x16 mfma16(bf16x8 a, bf16x8 b, f32x16 c) {
    return __builtin_amdgcn_mfma_f32_32x32x16_bf16(a, b, c, 0, 0, 0);
}

__device__ __forceinline__ float eluf(float v) { return v > 0.f ? v : expm1f(v); }

// ---------------- prep: combined conv kernel ----------------
__global__ __launch_bounds__(256) void make_K(const float* __restrict__ dw,
                                              const float* __restrict__ pw,
                                              float* __restrict__ K) {
    int i = blockIdx.x * 256 + threadIdx.x;
    if (i >= 3 * 27 * 27 * 4) return;
    int f = i & 3;
    int r = i >> 2;
    int dx = r % 27; r /= 27;
    int d  = r % 27;
    int c  = r / 27;
    float s = 0.f;
#pragma unroll
    for (int m = 0; m < 5; m++)
        s = fmaf(dw[((d * 27 + dx) * 3 + c) * 5 + m], pw[(c * 5 + m) * 4 + f], s);
    K[i] = s;
}

// ---------------- prep: B in MFMA-fragment order (bf16 hi/lo) -------------
// Bg2[s][plane][n][k16], s = (c*27+d)*2 + half; B[k][n] = K[c][d][xi-w+13][f]
__global__ __launch_bounds__(256) void make_B2(const float* __restrict__ K,
                                               unsigned short* __restrict__ Bg) {
    int gid = blockIdx.x * 256 + threadIdx.x;
    if (gid >= 162 * 128) return;
    int n = gid & 127;
    int s = gid >> 7;
    int half = s & 1;
    int cd = s >> 1;
    int c = cd / 27, d = cd % 27;
    int w = n >> 2, f = n & 3;
    unsigned short* dsth = Bg + (size_t)s * 4096 + n * 16;   // ushort units
    unsigned short* dstl = dsth + 2048;
#pragma unroll
    for (int k = 0; k < 16; k++) {
        int xi = half * 16 + k;
        int dx = xi - w + 13;
        float v = (dx >= 0 && dx < 27) ? K[((c * 27 + d) * 27 + dx) * 4 + f] : 0.f;
        __bf16 h = (__bf16)v;
        __bf16 l = (__bf16)(v - (float)h);
        dsth[k] = __builtin_bit_cast(unsigned short, h);
        dstl[k] = __builtin_bit_cast(unsigned short, l);
    }
}

// ---------------- prep: reorder W_td -> Wtdr[tt][row][k][j] ----------------
__global__ __launch_bounds__(256) void reorder_Wtd(const float* __restrict__ Wtd,
                                                   float* __restrict__ Wtdr) {
    int gid = blockIdx.x * 256 + threadIdx.x;
    if (gid >= 40960) return;
    int j = gid % 10;
    int r = gid / 10;
    int k = r & 3; r >>= 2;
    int row = r & 31;
    int tt = r >> 5;
    Wtdr[gid] = Wtd[(size_t)(row * 128 + tt * 4 + k) * 10 + j];
}

// ---------------- LSTM branch ----------------------------------------------
__global__ __launch_bounds__(256) void lstm_td(const float* __restrict__ x,
                                               const float* __restrict__ W,
                                               const float* __restrict__ U,
                                               const float* __restrict__ Wtdr,
                                               float* __restrict__ td_out) {
    __shared__ float sW[48];
    __shared__ float sU[64];
    int t = threadIdx.x;
    if (t < 48) sW[t] = W[t];
    else if (t >= 128 && t < 192) sU[t - 128] = U[t - 128];
    __syncthreads();

    int n = blockIdx.x * 256 + t;   // n = b*32 + row
    int row = n & 31;
    const float4* xp4 = (const float4*)(x + (size_t)n * 96);

    float h0 = 0, h1 = 0, h2 = 0, h3 = 0;
    float c0 = 0, c1 = 0, c2 = 0, c3 = 0;
    float acc[10];
#pragma unroll
    for (int j = 0; j < 10; j++) acc[j] = 0.f;

    for (int g = 0; g < 8; g++) {
        float4 q0 = xp4[g * 3 + 0], q1 = xp4[g * 3 + 1], q2 = xp4[g * 3 + 2];
        float xr[12] = {q0.x, q0.y, q0.z, q0.w, q1.x, q1.y,
                        q1.z, q1.w, q2.x, q2.y, q2.z, q2.w};
#pragma unroll
        for (int st = 0; st < 4; st++) {
            int tt = g * 4 + st;
            float x0 = xr[st * 3 + 0], x1 = xr[st * 3 + 1], x2 = xr[st * 3 + 2];
            float z[16];
#pragma unroll
            for (int k = 0; k < 16; k++)
                z[k] = x0 * sW[k] + x1 * sW[16 + k] + x2 * sW[32 + k]
                     + h0 * sU[k] + h1 * sU[16 + k] + h2 * sU[32 + k] + h3 * sU[48 + k];

            float ig0 = eluf(z[0]),  ig1 = eluf(z[1]),  ig2 = eluf(z[2]),  ig3 = eluf(z[3]);
            float fg0 = eluf(z[4]),  fg1 = eluf(z[5]),  fg2 = eluf(z[6]),  fg3 = eluf(z[7]);
            float og0 = eluf(z[12]), og1 = eluf(z[13]), og2 = eluf(z[14]), og3 = eluf(z[15]);

            float zm = fmaxf(fmaxf(z[8], z[9]), fmaxf(z[10], z[11]));
            float e0 = expf(z[8] - zm), e1 = expf(z[9] - zm);
            float e2 = expf(z[10] - zm), e3 = expf(z[11] - zm);
            float inv = 1.f / (e0 + e1 + e2 + e3);
            c0 = fg0 * c0 + ig0 * (e0 * inv);
            c1 = fg1 * c1 + ig1 * (e1 * inv);
            c2 = fg2 * c2 + ig2 * (e2 * inv);
            c3 = fg3 * c3 + ig3 * (e3 * inv);

            float cm = fmaxf(fmaxf(c0, c1), fmaxf(c2, c3));
            float q0e = expf(c0 - cm), q1e = expf(c1 - cm);
            float q2e = expf(c2 - cm), q3e = expf(c3 - cm);
            float qinv = 1.f / (q0e + q1e + q2e + q3e);
            h0 = og0 * (q0e * qinv); h1 = og1 * (q1e * qinv);
            h2 = og2 * (q2e * qinv); h3 = og3 * (q3e * qinv);

            // Wtdr[tt][row][k][j] : 40 contiguous floats, 10x float4
            const float4* wr4 = (const float4*)(Wtdr + tt * 1280 + row * 40);
            float wv[40];
#pragma unroll
            for (int i = 0; i < 10; i++) {
                float4 q = wr4[i];
                wv[i * 4 + 0] = q.x; wv[i * 4 + 1] = q.y;
                wv[i * 4 + 2] = q.z; wv[i * 4 + 3] = q.w;
            }
#pragma unroll
            for (int j = 0; j < 10; j++)
                acc[j] += h0 * wv[j] + h1 * wv[10 + j] + h2 * wv[20 + j] + h3 * wv[30 + j];
        }
    }

#pragma unroll
    for (int off = 16; off >= 1; off >>= 1) {
#pragma unroll
        for (int j = 0; j < 10; j++) acc[j] += __shfl_xor(acc[j], off, 64);
    }
    int lane = t & 63;
    if (lane == 0 || lane == 32) {
        int b = n >> 5;
#pragma unroll
        for (int j = 0; j < 10; j++) td_out[b * 10 + j] = acc[j];
    }
}

// ---------------- conv branch: barrier-free MFMA implicit GEMM -------------
// Block = 4 images, 4 waves; wave = 2 img x 2 N-tiles.
// A in LDS (staged once). B read per-wave from global in fragment order,
// 1-chunk register prefetch; NO barriers in the K-loop.
#define A_OFF 0
#define ZOFF 52224           /* 128 B zero row */
#define SRED_OFF 52352       /* 4 waves * 2 img * 10 floats */
#define LDS_BYTES 52512

__global__ __launch_bounds__(256, 3) void conv_sc(const float* __restrict__ x,
                                                  const unsigned short* __restrict__ Bg,
                                                  const float* __restrict__ Wsc,
                                                  const float* __restrict__ bias,
                                                  float* __restrict__ sc_out) {
    __shared__ char LDS[LDS_BYTES] __attribute__((aligned(16)));
    int t = threadIdx.x;
    int l = t & 63;
    int wv = t >> 6;
    int m = l & 31;
    int sub = (l >> 5) * 16;   // byte offset of k-half within a 16-elem bf16 run

    // ---- stage A: 4 images -> bf16 hi/lo planes, 136 B row records ----
    const float* xb = x + (size_t)blockIdx.x * 12288;
    for (int img = 0; img < 4; img++) {
        const float4* xi4 = (const float4*)(xb + img * 3072);
#pragma unroll
        for (int i = 0; i < 3; i++) {
            int fi = i * 256 + t;
            float4 q = xi4[fi];
            float vals[4] = {q.x, q.y, q.z, q.w};
            int p = fi * 4;
#pragma unroll
            for (int e = 0; e < 4; e++) {
                int pe = p + e;
                int c = pe % 3;
                int hw = pe / 3;
                int wc = hw & 31;
                int hr = hw >> 5;
                int rec = A_OFF + ((img * 3 + c) * 32 + hr) * 136 + wc * 2;
                float v = vals[e];
                __bf16 hb = (__bf16)v;
                __bf16 lb = (__bf16)(v - (float)hb);
                *(__bf16*)(LDS + rec) = hb;
                *(__bf16*)(LDS + rec + 64) = lb;
            }
        }
    }
    if (t < 32) *(float*)(LDS + ZOFF + t * 4) = 0.f;
    __syncthreads();   // the only barrier before the epilogue

    int imgpair = wv >> 1;
    int img0 = imgpair * 2;
    int ntbase = (wv & 1) * 2;

    // per-lane B base: plane-hi ntile0 fragment address
    const char* bbase = (const char*)Bg + (size_t)ntbase * 1024 + m * 32 + sub;

    BF4 cur[4], nxt[4];
#define LOADB(sv, arr) { const char* p_ = bbase + (size_t)(sv) * 8192;       \
        arr[0].f = *(const float4*)(p_);                                     \
        arr[1].f = *(const float4*)(p_ + 4096);                              \
        arr[2].f = *(const float4*)(p_ + 1024);                              \
        arr[3].f = *(const float4*)(p_ + 4096 + 1024); }

    LOADB(0, cur);

    f32x16 acc00 = {0,0,0,0,0,0,0,0,0,0,0,0,0,0,0,0};
    f32x16 acc01 = acc00, acc10 = acc00, acc11 = acc00;

    int c = 0, d = 0, half = 0;
    for (int s = 0; s < 162; s++) {
        if (s < 161) LOADB(s + 1, nxt);

        // A fragments (vertical SAME via zero-row select)
        int rowIdx = m + d - 13;
        bool valid = (unsigned)rowIdx < 32u;
        int aoff = A_OFF + ((img0 * 3 + c) * 32 + rowIdx) * 136 + half * 32 + sub;
        int base0 = valid ? aoff : ZOFF;
        int base1 = valid ? (aoff + 13056) : ZOFF;

        FragU ah0, al0, ah1, al1;
        ah0.u2[0] = *(const uint2*)(LDS + base0);
        ah0.u2[1] = *(const uint2*)(LDS + base0 + 8);
        al0.u2[0] = *(const uint2*)(LDS + base0 + 64);
        al0.u2[1] = *(const uint2*)(LDS + base0 + 72);
        ah1.u2[0] = *(const uint2*)(LDS + base1);
        ah1.u2[1] = *(const uint2*)(LDS + base1 + 8);
        al1.u2[0] = *(const uint2*)(LDS + base1 + 64);
        al1.u2[1] = *(const uint2*)(LDS + base1 + 72);

        // 3-product bf16 split: hh + hl + lh
        acc00 = mfma16(ah0.v, cur[0].v, acc00);
        acc00 = mfma16(ah0.v, cur[1].v, acc00);
        acc00 = mfma16(al0.v, cur[0].v, acc00);
        acc01 = mfma16(ah0.v, cur[2].v, acc01);
        acc01 = mfma16(ah0.v, cur[3].v, acc01);
        acc01 = mfma16(al0.v, cur[2].v, acc01);
        acc10 = mfma16(ah1.v, cur[0].v, acc10);
        acc10 = mfma16(ah1.v, cur[1].v, acc10);
        acc10 = mfma16(al1.v, cur[0].v, acc10);
        acc11 = mfma16(ah1.v, cur[2].v, acc11);
        acc11 = mfma16(ah1.v, cur[3].v, acc11);
        acc11 = mfma16(al1.v, cur[2].v, acc11);

#pragma unroll
        for (int i = 0; i < 4; i++) cur[i] = nxt[i];
        half ^= 1;
        if (!half) { d++; if (d == 27) { d = 0; c++; } }
    }

    // ---- epilogue: bias + sigmoid + W_sc partial dot + reductions ----
    float b4[4];
#pragma unroll
    for (int i = 0; i < 4; i++) b4[i] = bias[i];

    float part[2][10];
#pragma unroll
    for (int i = 0; i < 2; i++)
#pragma unroll
        for (int j = 0; j < 10; j++) part[i][j] = 0.f;

    f32x16 accs[2][2] = {{acc00, acc01}, {acc10, acc11}};
#pragma unroll
    for (int i2 = 0; i2 < 2; i2++) {
#pragma unroll
        for (int j2 = 0; j2 < 2; j2++) {
            int ncol = (ntbase + j2) * 32 + m;
            int wcol = ncol >> 2;
            int f = ncol & 3;
            f32x16 a = accs[i2][j2];
#pragma unroll
            for (int r = 0; r < 16; r++) {
                int h = (r & 3) + 8 * (r >> 2) + 4 * (l >> 5);
                float v = a[r] + b4[f];
                float sg = 1.f / (1.f + expf(-v));
                const float* wr = Wsc + (size_t)((h * 32 + wcol) * 4 + f) * 10;
#pragma unroll
                for (int j = 0; j < 10; j++) part[i2][j] = fmaf(sg, wr[j], part[i2][j]);
            }
        }
    }

#pragma unroll
    for (int off = 32; off >= 1; off >>= 1) {
#pragma unroll
        for (int i2 = 0; i2 < 2; i2++)
#pragma unroll
            for (int j = 0; j < 10; j++) part[i2][j] += __shfl_xor(part[i2][j], off, 64);
    }
    if (l == 0) {
        float* red = (float*)(LDS + SRED_OFF);
#pragma unroll
        for (int i2 = 0; i2 < 2; i2++)
#pragma unroll
            for (int j = 0; j < 10; j++) red[(wv * 2 + i2) * 10 + j] = part[i2][j];
    }
    __syncthreads();
    if (t < 40) {
        int img = t / 10, j = t % 10;
        const float* red = (const float*)(LDS + SRED_OFF);
        int pair = img >> 1, i2 = img & 1;
        float sv = red[((pair * 2) * 2 + i2) * 10 + j] + red[((pair * 2 + 1) * 2 + i2) * 10 + j];
        sc_out[(blockIdx.x * 4 + img) * 10 + j] = sv;
    }
}

__global__ __launch_bounds__(256) void finalize(const float* __restrict__ td,
                                                const float* __restrict__ sc,
                                                float* __restrict__ out, int n) {
    int i = blockIdx.x * 256 + threadIdx.x;
    if (i < n) {
        float a = td[i], s = sc[i];
        float tol = 1e-6f + 1e-6f * fabsf(s);
        out[i] = (fabsf(a - s) <= tol) ? 1.0f : 0.0f;
    }
}

extern "C" void kernel_launch(void* const* d_in, const int* in_sizes, int n_in,
                              void* d_out, int out_size, void* d_ws, size_t ws_size,
                              hipStream_t stream) {
    const float* x    = (const float*)d_in[0];
    const float* W    = (const float*)d_in[1];
    const float* U    = (const float*)d_in[2];
    const float* dw   = (const float*)d_in[3];
    const float* pw   = (const float*)d_in[4];
    const float* bias = (const float*)d_in[5];
    const float* Wtd  = (const float*)d_in[6];
    const float* Wsc  = (const float*)d_in[7];

    float* ws     = (float*)d_ws;
    float* td_acc = ws + TD_OFF;
    float* sc_acc = ws + SC_OFF;
    float* K      = ws + K_OFF;
    float* Wtdr   = ws + WTDR_OFF;
    unsigned short* Bg = (unsigned short*)((char*)d_ws + BG_BYTE_OFF);

    make_K<<<(3 * 27 * 27 * 4 + 255) / 256, 256, 0, stream>>>(dw, pw, K);
    make_B2<<<(162 * 128 + 255) / 256, 256, 0, stream>>>(K, Bg);
    reorder_Wtd<<<160, 256, 0, stream>>>(Wtd, Wtdr);
    lstm_td<<<512, 256, 0, stream>>>(x, W, U, Wtdr, td_acc);
    conv_sc<<<1024, 256, 0, stream>>>(x, Bg, Wsc, bias, sc_acc);
    finalize<<<(out_size + 255) / 256, 256, 0, stream>>>(td_acc, sc_acc, (float*)d_out, out_size);
}

// Round 4
// 400.871 us; speedup vs baseline: 2.1152x; 1.0637x over previous
//
#include <hip/hip_runtime.h>
#include <math.h>

// ---------------- Workspace layout ----------------
// floats:   [0, 40960)        td accumulator (4096 x 10)
//           [40960, 81920)    Wtdr[tt][row][j][k] reordered W_td
// bytes:    [524288, 524288+1359872)  Bg: bf16 hi/lo B slabs in MFMA-fragment
//           order, Bg[s][plane][n][16k]; slab 8192 B; 162 real + 4 pad slabs
#define TD_OFF 0
#define WTDR_OFF 40960
#define BG_BYTE_OFF 524288

typedef __bf16 bf16x8 __attribute__((ext_vector_type(8)));
typedef float f32x16 __attribute__((ext_vector_type(16)));

union FragU { bf16x8 v; uint2 u2[2]; };
union BF4  { float4 f; bf16x8 v; };

__device__ __forceinline__ f32x16 mfma16(bf16x8 a, bf16x8 b, f32x16 c) {
    return __builtin_amdgcn_mfma_f32_32x32x16_bf16(a, b, c, 0, 0, 0);
}

__device__ __forceinline__ float eluf(float v) {
    return v > 0.f ? v : __expf(v) - 1.f;
}

// ---------------- prep: Wtdr reorder + B matrix (K computed inline) --------
// part 1 (gid < 40960):  Wtdr[((tt*32+row)*10+j)*4+k] = Wtd[(row*128+tt*4+k)*10+j]
// part 2 (next 162*128): Bg[s][plane][n][16k]; B[k][n] = K[c][d][xi-w+13][f],
//   K[c][d][dx][f] = sum_m dw[((d*27+dx)*3+c)*5+m] * pw[(c*5+m)*4+f]
__global__ __launch_bounds__(256) void prep(const float* __restrict__ dw,
                                            const float* __restrict__ pw,
                                            const float* __restrict__ Wtd,
                                            float* __restrict__ Wtdr,
                                            unsigned short* __restrict__ Bg) {
    int gid = blockIdx.x * 256 + threadIdx.x;
    if (gid < 40960) {
        int k = gid & 3;
        int r = gid >> 2;
        int j = r % 10; r /= 10;
        int row = r & 31;
        int tt = r >> 5;
        Wtdr[gid] = Wtd[(size_t)(row * 128 + tt * 4 + k) * 10 + j];
        return;
    }
    int g2 = gid - 40960;
    if (g2 >= 162 * 128) return;
    int n = g2 & 127;
    int s = g2 >> 7;
    int half = s & 1;
    int cd = s >> 1;
    int c = cd / 27, d = cd % 27;
    int w = n >> 2, f = n & 3;
    unsigned short* dsth = Bg + (size_t)s * 4096 + n * 16;   // ushort units
    unsigned short* dstl = dsth + 2048;
#pragma unroll
    for (int k = 0; k < 16; k++) {
        int xi = half * 16 + k;
        int dx = xi - w + 13;
        float v = 0.f;
        if (dx >= 0 && dx < 27) {
#pragma unroll
            for (int m = 0; m < 5; m++)
                v = fmaf(dw[((d * 27 + dx) * 3 + c) * 5 + m], pw[(c * 5 + m) * 4 + f], v);
        }
        __bf16 h = (__bf16)v;
        __bf16 l = (__bf16)(v - (float)h);
        dsth[k] = __builtin_bit_cast(unsigned short, h);
        dstl[k] = __builtin_bit_cast(unsigned short, l);
    }
}

// ---------------- LSTM branch: no LDS, W/U uniform (SGPR) ------------------
__global__ __launch_bounds__(256) void lstm_td(const float* __restrict__ x,
                                               const float* __restrict__ W,
                                               const float* __restrict__ U,
                                               const float* __restrict__ Wtdr,
                                               float* __restrict__ td_out) {
    // wave-uniform loads -> scalar registers
    float rW[48], rU[64];
    const float4* W4 = (const float4*)W;
    const float4* U4 = (const float4*)U;
#pragma unroll
    for (int i = 0; i < 12; i++) {
        float4 q = W4[i];
        rW[i * 4 + 0] = q.x; rW[i * 4 + 1] = q.y;
        rW[i * 4 + 2] = q.z; rW[i * 4 + 3] = q.w;
    }
#pragma unroll
    for (int i = 0; i < 16; i++) {
        float4 q = U4[i];
        rU[i * 4 + 0] = q.x; rU[i * 4 + 1] = q.y;
        rU[i * 4 + 2] = q.z; rU[i * 4 + 3] = q.w;
    }

    int t = threadIdx.x;
    int n = blockIdx.x * 256 + t;   // n = b*32 + row
    int row = n & 31;
    const float4* xp4 = (const float4*)(x + (size_t)n * 96);

    float h0 = 0, h1 = 0, h2 = 0, h3 = 0;
    float c0 = 0, c1 = 0, c2 = 0, c3 = 0;
    float acc[10];
#pragma unroll
    for (int j = 0; j < 10; j++) acc[j] = 0.f;

    for (int g = 0; g < 8; g++) {
        float4 q0 = xp4[g * 3 + 0], q1 = xp4[g * 3 + 1], q2 = xp4[g * 3 + 2];
        float xr[12] = {q0.x, q0.y, q0.z, q0.w, q1.x, q1.y,
                        q1.z, q1.w, q2.x, q2.y, q2.z, q2.w};
#pragma unroll
        for (int st = 0; st < 4; st++) {
            int tt = g * 4 + st;
            float x0 = xr[st * 3 + 0], x1 = xr[st * 3 + 1], x2 = xr[st * 3 + 2];
            float z[16];
#pragma unroll
            for (int k = 0; k < 16; k++)
                z[k] = x0 * rW[k] + x1 * rW[16 + k] + x2 * rW[32 + k]
                     + h0 * rU[k] + h1 * rU[16 + k] + h2 * rU[32 + k] + h3 * rU[48 + k];

            float ig0 = eluf(z[0]),  ig1 = eluf(z[1]),  ig2 = eluf(z[2]),  ig3 = eluf(z[3]);
            float fg0 = eluf(z[4]),  fg1 = eluf(z[5]),  fg2 = eluf(z[6]),  fg3 = eluf(z[7]);
            float og0 = eluf(z[12]), og1 = eluf(z[13]), og2 = eluf(z[14]), og3 = eluf(z[15]);

            float zm = fmaxf(fmaxf(z[8], z[9]), fmaxf(z[10], z[11]));
            float e0 = __expf(z[8] - zm), e1 = __expf(z[9] - zm);
            float e2 = __expf(z[10] - zm), e3 = __expf(z[11] - zm);
            float inv = 1.f / (e0 + e1 + e2 + e3);
            c0 = fg0 * c0 + ig0 * (e0 * inv);
            c1 = fg1 * c1 + ig1 * (e1 * inv);
            c2 = fg2 * c2 + ig2 * (e2 * inv);
            c3 = fg3 * c3 + ig3 * (e3 * inv);

            float cm = fmaxf(fmaxf(c0, c1), fmaxf(c2, c3));
            float p0 = __expf(c0 - cm), p1 = __expf(c1 - cm);
            float p2 = __expf(c2 - cm), p3 = __expf(c3 - cm);
            float pinv = 1.f / (p0 + p1 + p2 + p3);
            h0 = og0 * (p0 * pinv); h1 = og1 * (p1 * pinv);
            h2 = og2 * (p2 * pinv); h3 = og3 * (p3 * pinv);

            // Wtdr[tt][row][j][k]: one float4 per j
            const float4* wr4 = (const float4*)(Wtdr + (size_t)(tt * 32 + row) * 40);
#pragma unroll
            for (int j = 0; j < 10; j++) {
                float4 q = wr4[j];
                acc[j] += h0 * q.x + h1 * q.y + h2 * q.z + h3 * q.w;
            }
        }
    }

#pragma unroll
    for (int off = 16; off >= 1; off >>= 1) {
#pragma unroll
        for (int j = 0; j < 10; j++) acc[j] += __shfl_xor(acc[j], off, 64);
    }
    int lane = t & 63;
    if (lane == 0 || lane == 32) {
        int b = n >> 5;
#pragma unroll
        for (int j = 0; j < 10; j++) td_out[b * 10 + j] = acc[j];
    }
}

// ---------------- conv branch: depth-3-prefetch MFMA implicit GEMM ---------
// Block = 4 images, 4 waves; wave = 2 img x 2 N-tiles. A in LDS (staged once).
// B read per-wave from global, 3-deep register rotation, no in-loop barriers.
// Epilogue: bias+sigmoid+W_sc dot, then fused |td-sc|<=tol boolean write.
#define A_OFF 0
#define ZOFF 52224           /* 128 B zero row */
#define SRED_OFF 52352       /* 4 waves * 2 img * 10 floats */
#define LDS_BYTES 52512

__global__ __launch_bounds__(256, 3) void conv_sc(const float* __restrict__ x,
                                                  const unsigned short* __restrict__ Bg,
                                                  const float* __restrict__ Wsc,
                                                  const float* __restrict__ bias,
                                                  const float* __restrict__ td,
                                                  float* __restrict__ out) {
    __shared__ char LDS[LDS_BYTES] __attribute__((aligned(16)));
    int t = threadIdx.x;
    int l = t & 63;
    int wv = t >> 6;
    int m = l & 31;
    int sub = (l >> 5) * 16;   // byte offset of k-half within a 16-elem bf16 run

    int imgpair = wv >> 1;
    int img0 = imgpair * 2;
    int ntbase = (wv & 1) * 2;

    const char* bbase = (const char*)Bg + (size_t)ntbase * 1024 + m * 32 + sub;
    BF4 bufA[4], bufB[4], bufC[4];
#define LOADB(sv, arr) { const char* p_ = bbase + (size_t)(sv) * 8192;       \
        arr[0].f = *(const float4*)(p_);                                     \
        arr[1].f = *(const float4*)(p_ + 4096);                              \
        arr[2].f = *(const float4*)(p_ + 1024);                              \
        arr[3].f = *(const float4*)(p_ + 5120); }

    LOADB(0, bufA);
    LOADB(1, bufB);

    // ---- stage A: 4 images -> bf16 hi/lo planes, 136 B row records ----
    const float* xb = x + (size_t)blockIdx.x * 12288;
    for (int img = 0; img < 4; img++) {
        const float4* xi4 = (const float4*)(xb + img * 3072);
#pragma unroll
        for (int i = 0; i < 3; i++) {
            int fi = i * 256 + t;
            float4 q = xi4[fi];
            float vals[4] = {q.x, q.y, q.z, q.w};
            int p = fi * 4;
#pragma unroll
            for (int e = 0; e < 4; e++) {
                int pe = p + e;
                int c = pe % 3;
                int hw = pe / 3;
                int wc = hw & 31;
                int hr = hw >> 5;
                int rec = A_OFF + ((img * 3 + c) * 32 + hr) * 136 + wc * 2;
                float v = vals[e];
                __bf16 hb = (__bf16)v;
                __bf16 lb = (__bf16)(v - (float)hb);
                *(__bf16*)(LDS + rec) = hb;
                *(__bf16*)(LDS + rec + 64) = lb;
            }
        }
    }
    if (t < 32) *(float*)(LDS + ZOFF + t * 4) = 0.f;
    __syncthreads();   // the only barrier before the epilogue

    f32x16 acc00 = {0,0,0,0,0,0,0,0,0,0,0,0,0,0,0,0};
    f32x16 acc01 = acc00, acc10 = acc00, acc11 = acc00;

    int c = 0, d = 0, half = 0;

#define CHUNK(USE, DST, SNEXT) {                                              \
    LOADB(SNEXT, DST);                                                        \
    int rowIdx = m + d - 13;                                                  \
    bool valid = (unsigned)rowIdx < 32u;                                      \
    int aoff = A_OFF + ((img0 * 3 + c) * 32 + rowIdx) * 136 + half * 32 + sub;\
    int base0 = valid ? aoff : ZOFF;                                          \
    int base1 = valid ? (aoff + 13056) : ZOFF;                                \
    FragU ah0, al0, ah1, al1;                                                 \
    ah0.u2[0] = *(const uint2*)(LDS + base0);                                 \
    ah0.u2[1] = *(const uint2*)(LDS + base0 + 8);                             \
    al0.u2[0] = *(const uint2*)(LDS + base0 + 64);                            \
    al0.u2[1] = *(const uint2*)(LDS + base0 + 72);                            \
    ah1.u2[0] = *(const uint2*)(LDS + base1);                                 \
    ah1.u2[1] = *(const uint2*)(LDS + base1 + 8);                             \
    al1.u2[0] = *(const uint2*)(LDS + base1 + 64);                            \
    al1.u2[1] = *(const uint2*)(LDS + base1 + 72);                            \
    acc00 = mfma16(ah0.v, USE[0].v, acc00);                                   \
    acc01 = mfma16(ah0.v, USE[2].v, acc01);                                   \
    acc10 = mfma16(ah1.v, USE[0].v, acc10);                                   \
    acc11 = mfma16(ah1.v, USE[2].v, acc11);                                   \
    acc00 = mfma16(ah0.v, USE[1].v, acc00);                                   \
    acc01 = mfma16(ah0.v, USE[3].v, acc01);                                   \
    acc10 = mfma16(ah1.v, USE[1].v, acc10);                                   \
    acc11 = mfma16(ah1.v, USE[3].v, acc11);                                   \
    acc00 = mfma16(al0.v, USE[0].v, acc00);                                   \
    acc01 = mfma16(al0.v, USE[2].v, acc01);                                   \
    acc10 = mfma16(al1.v, USE[0].v, acc10);                                   \
    acc11 = mfma16(al1.v, USE[2].v, acc11);                                   \
    half ^= 1;                                                                \
    if (!half) { d++; if (d == 27) { d = 0; c++; } }                          \
}

    for (int g = 0; g < 54; g++) {
        CHUNK(bufA, bufC, 3 * g + 2);
        CHUNK(bufB, bufA, 3 * g + 3);
        CHUNK(bufC, bufB, 3 * g + 4);
    }

    // ---- epilogue: bias + sigmoid + W_sc partial dot + reductions ----
    float b4[4];
#pragma unroll
    for (int i = 0; i < 4; i++) b4[i] = bias[i];

    float part[2][10];
#pragma unroll
    for (int i = 0; i < 2; i++)
#pragma unroll
        for (int j = 0; j < 10; j++) part[i][j] = 0.f;

    f32x16 accs[2][2] = {{acc00, acc01}, {acc10, acc11}};
#pragma unroll
    for (int i2 = 0; i2 < 2; i2++) {
#pragma unroll
        for (int j2 = 0; j2 < 2; j2++) {
            int ncol = (ntbase + j2) * 32 + m;
            int wcol = ncol >> 2;
            int f = ncol & 3;
            f32x16 a = accs[i2][j2];
#pragma unroll
            for (int r = 0; r < 16; r++) {
                int h = (r & 3) + 8 * (r >> 2) + 4 * (l >> 5);
                float v = a[r] + b4[f];
                float sg = 1.f / (1.f + expf(-v));
                const float* wr = Wsc + (size_t)((h * 32 + wcol) * 4 + f) * 10;
#pragma unroll
                for (int j = 0; j < 10; j++) part[i2][j] = fmaf(sg, wr[j], part[i2][j]);
            }
        }
    }

#pragma unroll
    for (int off = 32; off >= 1; off >>= 1) {
#pragma unroll
        for (int i2 = 0; i2 < 2; i2++)
#pragma unroll
            for (int j = 0; j < 10; j++) part[i2][j] += __shfl_xor(part[i2][j], off, 64);
    }
    if (l == 0) {
        float* red = (float*)(LDS + SRED_OFF);
#pragma unroll
        for (int i2 = 0; i2 < 2; i2++)
#pragma unroll
            for (int j = 0; j < 10; j++) red[(wv * 2 + i2) * 10 + j] = part[i2][j];
    }
    __syncthreads();
    if (t < 40) {
        int img = t / 10, j = t % 10;
        const float* red = (const float*)(LDS + SRED_OFF);
        int pair = img >> 1, i2 = img & 1;
        float sv = red[((pair * 2) * 2 + i2) * 10 + j] + red[((pair * 2 + 1) * 2 + i2) * 10 + j];
        int oi = (blockIdx.x * 4 + img) * 10 + j;
        float a = td[oi];
        float tol = 1e-6f + 1e-6f * fabsf(sv);
        out[oi] = (fabsf(a - sv) <= tol) ? 1.0f : 0.0f;
    }
}

extern "C" void kernel_launch(void* const* d_in, const int* in_sizes, int n_in,
                              void* d_out, int out_size, void* d_ws, size_t ws_size,
                              hipStream_t stream) {
    const float* x    = (const float*)d_in[0];
    const float* W    = (const float*)d_in[1];
    const float* U    = (const float*)d_in[2];
    const float* dw   = (const float*)d_in[3];
    const float* pw   = (const float*)d_in[4];
    const float* bias = (const float*)d_in[5];
    const float* Wtd  = (const float*)d_in[6];
    const float* Wsc  = (const float*)d_in[7];

    float* ws     = (float*)d_ws;
    float* td_acc = ws + TD_OFF;
    float* Wtdr   = ws + WTDR_OFF;
    unsigned short* Bg = (unsigned short*)((char*)d_ws + BG_BYTE_OFF);

    prep<<<(40960 + 162 * 128 + 255) / 256, 256, 0, stream>>>(dw, pw, Wtd, Wtdr, Bg);
    lstm_td<<<512, 256, 0, stream>>>(x, W, U, Wtdr, td_acc);
    conv_sc<<<1024, 256, 0, stream>>>(x, Bg, Wsc, bias, td_acc, (float*)d_out);
}

// Round 5
// 400.045 us; speedup vs baseline: 2.1195x; 1.0021x over previous
//
#include <hip/hip_runtime.h>
#include <math.h>

// ---------------- Workspace layout ----------------
// floats:   [0, 40960)        td accumulator (4096 x 10)
//           [40960, 81920)    Wtdr[tt][row][j][k] reordered W_td
// bytes:    [524288, +166*8192)  Bg: bf16 hi/lo B slabs in MFMA-fragment
//           order, Bg[s][plane][n][16k]; slab 8192 B; 162 real + pad slabs
#define TD_OFF 0
#define WTDR_OFF 40960
#define BG_BYTE_OFF 524288

typedef __bf16 bf16x8 __attribute__((ext_vector_type(8)));
typedef float f32x16 __attribute__((ext_vector_type(16)));

union FragU { bf16x8 v; float4 f; };

__device__ __forceinline__ f32x16 mfma16(bf16x8 a, bf16x8 b, f32x16 c) {
    return __builtin_amdgcn_mfma_f32_32x32x16_bf16(a, b, c, 0, 0, 0);
}

__device__ __forceinline__ float eluf(float v) {
    return v > 0.f ? v : __expf(v) - 1.f;
}

// ---------------- combined LSTM + prep kernel ------------------------------
// blocks [0,512): LSTM branch. blocks [512,753): prep (Wtdr reorder + Bg build).
__global__ __launch_bounds__(256) void lstm_prep(const float* __restrict__ x,
                                                 const float* __restrict__ W,
                                                 const float* __restrict__ U,
                                                 const float* __restrict__ Wtd,
                                                 const float* __restrict__ dw,
                                                 const float* __restrict__ pw,
                                                 float* __restrict__ Wtdr,
                                                 unsigned short* __restrict__ Bg,
                                                 float* __restrict__ td_out) {
    int t = threadIdx.x;
    if (blockIdx.x >= 512) {
        int gid = (blockIdx.x - 512) * 256 + t;
        if (gid < 40960) {
            int k = gid & 3;
            int r = gid >> 2;
            int j = r % 10; r /= 10;
            int row = r & 31;
            int tt = r >> 5;
            Wtdr[gid] = Wtd[(size_t)(row * 128 + tt * 4 + k) * 10 + j];
            return;
        }
        int g2 = gid - 40960;
        if (g2 >= 162 * 128) return;
        int n = g2 & 127;
        int s = g2 >> 7;
        int half = s & 1;
        int cd = s >> 1;
        int c = cd / 27, d = cd % 27;
        int w = n >> 2, f = n & 3;
        unsigned short* dsth = Bg + (size_t)s * 4096 + n * 16;   // ushort units
        unsigned short* dstl = dsth + 2048;
#pragma unroll
        for (int k = 0; k < 16; k++) {
            int xi = half * 16 + k;
            int dx = xi - w + 13;
            float v = 0.f;
            if (dx >= 0 && dx < 27) {
#pragma unroll
                for (int m = 0; m < 5; m++)
                    v = fmaf(dw[((d * 27 + dx) * 3 + c) * 5 + m],
                             pw[(c * 5 + m) * 4 + f], v);
            }
            __bf16 h = (__bf16)v;
            __bf16 l = (__bf16)(v - (float)h);
            dsth[k] = __builtin_bit_cast(unsigned short, h);
            dstl[k] = __builtin_bit_cast(unsigned short, l);
        }
        return;
    }

    // ---- LSTM path ----
    float rW[48], rU[64];
    const float4* W4 = (const float4*)W;
    const float4* U4 = (const float4*)U;
#pragma unroll
    for (int i = 0; i < 12; i++) {
        float4 q = W4[i];
        rW[i * 4 + 0] = q.x; rW[i * 4 + 1] = q.y;
        rW[i * 4 + 2] = q.z; rW[i * 4 + 3] = q.w;
    }
#pragma unroll
    for (int i = 0; i < 16; i++) {
        float4 q = U4[i];
        rU[i * 4 + 0] = q.x; rU[i * 4 + 1] = q.y;
        rU[i * 4 + 2] = q.z; rU[i * 4 + 3] = q.w;
    }

    int n = blockIdx.x * 256 + t;   // n = b*32 + row
    int row = n & 31;
    const float4* xp4 = (const float4*)(x + (size_t)n * 96);

    float h0 = 0, h1 = 0, h2 = 0, h3 = 0;
    float c0 = 0, c1 = 0, c2 = 0, c3 = 0;
    float acc[10];
#pragma unroll
    for (int j = 0; j < 10; j++) acc[j] = 0.f;

    for (int g = 0; g < 8; g++) {
        float4 q0 = xp4[g * 3 + 0], q1 = xp4[g * 3 + 1], q2 = xp4[g * 3 + 2];
        float xr[12] = {q0.x, q0.y, q0.z, q0.w, q1.x, q1.y,
                        q1.z, q1.w, q2.x, q2.y, q2.z, q2.w};
#pragma unroll
        for (int st = 0; st < 4; st++) {
            int tt = g * 4 + st;
            float x0 = xr[st * 3 + 0], x1 = xr[st * 3 + 1], x2 = xr[st * 3 + 2];
            float z[16];
#pragma unroll
            for (int k = 0; k < 16; k++)
                z[k] = x0 * rW[k] + x1 * rW[16 + k] + x2 * rW[32 + k]
                     + h0 * rU[k] + h1 * rU[16 + k] + h2 * rU[32 + k] + h3 * rU[48 + k];

            float ig0 = eluf(z[0]),  ig1 = eluf(z[1]),  ig2 = eluf(z[2]),  ig3 = eluf(z[3]);
            float fg0 = eluf(z[4]),  fg1 = eluf(z[5]),  fg2 = eluf(z[6]),  fg3 = eluf(z[7]);
            float og0 = eluf(z[12]), og1 = eluf(z[13]), og2 = eluf(z[14]), og3 = eluf(z[15]);

            float zm = fmaxf(fmaxf(z[8], z[9]), fmaxf(z[10], z[11]));
            float e0 = __expf(z[8] - zm), e1 = __expf(z[9] - zm);
            float e2 = __expf(z[10] - zm), e3 = __expf(z[11] - zm);
            float inv = 1.f / (e0 + e1 + e2 + e3);
            c0 = fg0 * c0 + ig0 * (e0 * inv);
            c1 = fg1 * c1 + ig1 * (e1 * inv);
            c2 = fg2 * c2 + ig2 * (e2 * inv);
            c3 = fg3 * c3 + ig3 * (e3 * inv);

            float cm = fmaxf(fmaxf(c0, c1), fmaxf(c2, c3));
            float p0 = __expf(c0 - cm), p1 = __expf(c1 - cm);
            float p2 = __expf(c2 - cm), p3 = __expf(c3 - cm);
            float pinv = 1.f / (p0 + p1 + p2 + p3);
            h0 = og0 * (p0 * pinv); h1 = og1 * (p1 * pinv);
            h2 = og2 * (p2 * pinv); h3 = og3 * (p3 * pinv);

            const float4* wr4 = (const float4*)(Wtdr + (size_t)(tt * 32 + row) * 40);
#pragma unroll
            for (int j = 0; j < 10; j++) {
                float4 q = wr4[j];
                acc[j] += h0 * q.x + h1 * q.y + h2 * q.z + h3 * q.w;
            }
        }
    }

#pragma unroll
    for (int off = 16; off >= 1; off >>= 1) {
#pragma unroll
        for (int j = 0; j < 10; j++) acc[j] += __shfl_xor(acc[j], off, 64);
    }
    int lane = t & 63;
    if (lane == 0 || lane == 32) {
        int b = n >> 5;
#pragma unroll
        for (int j = 0; j < 10; j++) td_out[b * 10 + j] = acc[j];
    }
}

// ---------------- conv branch: small-tile MFMA implicit GEMM ---------------
// Block = 2 images, 4 waves; wave = 2 img x 1 N-tile (acc = 32 regs).
// A in LDS, layout [img][c][plane][half][sub][row][16B] -> A-fragment reads
// are contiguous conflict-free ds_read_b128. B per-wave from global,
// depth-3 rotation, no in-loop barriers. Fused boolean epilogue.
#define A_OFF 0
#define ZOFF 24576           /* 16 B zeros */
#define SRED_OFF 24592       /* 4 waves * 2 img * 10 floats */
#define LDS_BYTES 24912

__global__ __launch_bounds__(256, 4) void conv_sc(const float* __restrict__ x,
                                                  const unsigned short* __restrict__ Bg,
                                                  const float* __restrict__ Wsc,
                                                  const float* __restrict__ bias,
                                                  const float* __restrict__ td,
                                                  float* __restrict__ out) {
    __shared__ char LDS[LDS_BYTES] __attribute__((aligned(16)));
    int t = threadIdx.x;
    int l = t & 63;
    int wv = t >> 6;          // ntile = wv
    int m = l & 31;
    int sub = l >> 5;         // k-subgroup (8 k's each)

    const char* bbase = (const char*)Bg + (size_t)wv * 1024 + m * 32 + sub * 16;
    FragU bufA[2], bufB[2], bufC[2];
#define LOADB(sv, arr) { const char* p_ = bbase + (size_t)(sv) * 8192;       \
        arr[0].f = *(const float4*)(p_);                                     \
        arr[1].f = *(const float4*)(p_ + 4096); }

    LOADB(0, bufA);
    LOADB(1, bufB);

    // ---- stage A: 2 images -> [img][c][plane][half][sub][row][16B] ----
    const float4* xb4 = (const float4*)(x + (size_t)blockIdx.x * 6144);
#pragma unroll
    for (int it = 0; it < 6; it++) {
        int fi = it * 256 + t;            // 1536 float4 per block
        float4 q = xb4[fi];
        float vals[4] = {q.x, q.y, q.z, q.w};
#pragma unroll
        for (int e = 0; e < 4; e++) {
            int pel = fi * 4 + e;
            int img = pel / 3072;
            int p = pel - img * 3072;
            int c = p % 3;
            int hw = p / 3;
            int w = hw & 31;
            int h = hw >> 5;
            // base with plane=0; plane stride = 2048
            int rec = A_OFF + (((img * 3 + c) * 8) + (w >> 4) * 2 + ((w >> 3) & 1)) * 512
                      + h * 16 + (w & 7) * 2;
            float v = vals[e];
            __bf16 hb = (__bf16)v;
            __bf16 lb = (__bf16)(v - (float)hb);
            *(__bf16*)(LDS + rec) = hb;
            *(__bf16*)(LDS + rec + 2048) = lb;
        }
    }
    if (t < 4) *(float*)(LDS + ZOFF + t * 4) = 0.f;
    __syncthreads();   // the only barrier before the epilogue

    f32x16 acc0 = {0,0,0,0,0,0,0,0,0,0,0,0,0,0,0,0};
    f32x16 acc1 = acc0;

    int c = 0, d = 0, half = 0;

#define CHUNK(USE, DST, SNEXT) {                                              \
    LOADB(SNEXT, DST);                                                        \
    int rowIdx = m + d - 13;                                                  \
    bool valid = (unsigned)rowIdx < 32u;                                      \
    int a0 = A_OFF + (c * 8 + half * 2 + sub) * 512 + rowIdx * 16;            \
    int ah0o = valid ? a0 : ZOFF;                                             \
    int al0o = valid ? (a0 + 2048) : ZOFF;                                    \
    int ah1o = valid ? (a0 + 12288) : ZOFF;                                   \
    int al1o = valid ? (a0 + 14336) : ZOFF;                                   \
    FragU ah0, al0, ah1, al1;                                                 \
    ah0.f = *(const float4*)(LDS + ah0o);                                     \
    al0.f = *(const float4*)(LDS + al0o);                                     \
    ah1.f = *(const float4*)(LDS + ah1o);                                     \
    al1.f = *(const float4*)(LDS + al1o);                                     \
    acc0 = mfma16(ah0.v, USE[0].v, acc0);                                     \
    acc1 = mfma16(ah1.v, USE[0].v, acc1);                                     \
    acc0 = mfma16(ah0.v, USE[1].v, acc0);                                     \
    acc1 = mfma16(ah1.v, USE[1].v, acc1);                                     \
    acc0 = mfma16(al0.v, USE[0].v, acc0);                                     \
    acc1 = mfma16(al1.v, USE[0].v, acc1);                                     \
    half ^= 1;                                                                \
    if (!half) { d++; if (d == 27) { d = 0; c++; } }                          \
}

    for (int g = 0; g < 54; g++) {
        CHUNK(bufA, bufC, 3 * g + 2);
        CHUNK(bufB, bufA, 3 * g + 3);
        CHUNK(bufC, bufB, 3 * g + 4);
    }

    // ---- epilogue: bias + sigmoid + W_sc partial dot + reductions ----
    float b4[4];
#pragma unroll
    for (int i = 0; i < 4; i++) b4[i] = bias[i];

    float part[2][10];
#pragma unroll
    for (int i = 0; i < 2; i++)
#pragma unroll
        for (int j = 0; j < 10; j++) part[i][j] = 0.f;

    f32x16 accs[2] = {acc0, acc1};
#pragma unroll
    for (int i2 = 0; i2 < 2; i2++) {
        int ncol = wv * 32 + m;
        int wcol = ncol >> 2;
        int f = ncol & 3;
        f32x16 a = accs[i2];
#pragma unroll
        for (int r = 0; r < 16; r++) {
            int h = (r & 3) + 8 * (r >> 2) + 4 * sub;
            float v = a[r] + b4[f];
            float sg = 1.f / (1.f + expf(-v));
            const float* wr = Wsc + (size_t)((h * 32 + wcol) * 4 + f) * 10;
#pragma unroll
            for (int j = 0; j < 10; j++) part[i2][j] = fmaf(sg, wr[j], part[i2][j]);
        }
    }

#pragma unroll
    for (int off = 32; off >= 1; off >>= 1) {
#pragma unroll
        for (int i2 = 0; i2 < 2; i2++)
#pragma unroll
            for (int j = 0; j < 10; j++) part[i2][j] += __shfl_xor(part[i2][j], off, 64);
    }
    if (l == 0) {
        float* red = (float*)(LDS + SRED_OFF);
#pragma unroll
        for (int i2 = 0; i2 < 2; i2++)
#pragma unroll
            for (int j = 0; j < 10; j++) red[(wv * 2 + i2) * 10 + j] = part[i2][j];
    }
    __syncthreads();
    if (t < 20) {
        int i2 = t / 10, j = t % 10;
        const float* red = (const float*)(LDS + SRED_OFF);
        float sv = red[(0 * 2 + i2) * 10 + j] + red[(1 * 2 + i2) * 10 + j]
                 + red[(2 * 2 + i2) * 10 + j] + red[(3 * 2 + i2) * 10 + j];
        int oi = (blockIdx.x * 2 + i2) * 10 + j;
        float a = td[oi];
        float tol = 1e-6f + 1e-6f * fabsf(sv);
        out[oi] = (fabsf(a - sv) <= tol) ? 1.0f : 0.0f;
    }
}

extern "C" void kernel_launch(void* const* d_in, const int* in_sizes, int n_in,
                              void* d_out, int out_size, void* d_ws, size_t ws_size,
                              hipStream_t stream) {
    const float* x    = (const float*)d_in[0];
    const float* W    = (const float*)d_in[1];
    const float* U    = (const float*)d_in[2];
    const float* dw   = (const float*)d_in[3];
    const float* pw   = (const float*)d_in[4];
    const float* bias = (const float*)d_in[5];
    const float* Wtd  = (const float*)d_in[6];
    const float* Wsc  = (const float*)d_in[7];

    float* ws     = (float*)d_ws;
    float* td_acc = ws + TD_OFF;
    float* Wtdr   = ws + WTDR_OFF;
    unsigned short* Bg = (unsigned short*)((char*)d_ws + BG_BYTE_OFF);

    lstm_prep<<<753, 256, 0, stream>>>(x, W, U, Wtd, dw, pw, Wtdr, Bg, td_acc);
    conv_sc<<<2048, 256, 0, stream>>>(x, Bg, Wsc, bias, td_acc, (float*)d_out);
}